// Round 5
// baseline (504.948 us; speedup 1.0000x reference)
//
#include <hip/hip_runtime.h>
#include <cstdint>
#include <cstddef>

#define LSEQ 4096
#define DMODEL 1152
#define NH 16
#define HD 72
#define HP96 96
#define HP80 80
#define NQKV 3456

typedef unsigned short u16;
typedef unsigned int u32;
typedef __attribute__((ext_vector_type(4))) float f32x4;
typedef __attribute__((ext_vector_type(4))) u32 u32x4;
typedef _Float16 f16x8 __attribute__((ext_vector_type(8), may_alias));
typedef unsigned short us8 __attribute__((ext_vector_type(8), may_alias));
typedef unsigned short us4 __attribute__((ext_vector_type(4), may_alias));

static __device__ __forceinline__ u16 f2h(float f) {
  _Float16 h = (_Float16)f;
  return __builtin_bit_cast(u16, h);
}
static __device__ __forceinline__ float h2f(u16 b) {
  return (float)__builtin_bit_cast(_Float16, b);
}

// ---------------- f32 -> f16 elementwise ----------------
__global__ void k_cvt_f16(const float* __restrict__ src, u16* __restrict__ dst, int n4) {
  int i = blockIdx.x * blockDim.x + threadIdx.x;
  int stride = gridDim.x * blockDim.x;
  for (; i < n4; i += stride) {
    float4 v = ((const float4*)src)[i];
    us4 o; o[0] = f2h(v.x); o[1] = f2h(v.y); o[2] = f2h(v.z); o[3] = f2h(v.w);
    ((us4*)dst)[i] = o;
  }
}

// ---------------- dst[n][k] = (f16) src[k][n]  (weight transpose) ----------------
__global__ void k_transp_w(const float* __restrict__ src, u16* __restrict__ dst, int K, int N) {
  __shared__ float tile[32][33];
  int tx = threadIdx.x & 31, ty = threadIdx.x >> 5;
  int n0 = blockIdx.x * 32, k0 = blockIdx.y * 32;
#pragma unroll
  for (int j = 0; j < 4; ++j)
    tile[ty + j * 8][tx] = src[(size_t)(k0 + ty + j * 8) * N + n0 + tx];
  __syncthreads();
#pragma unroll
  for (int j = 0; j < 4; ++j)
    dst[(size_t)(n0 + ty + j * 8) * K + k0 + tx] = f2h(tile[tx][ty + j * 8]);
}

// ---------------- C[M][N] = A[M][K] @ Bt[N][K]^T (+bias), f16 in, f16/f32 out ----------------
template <bool OUTF32>
__global__ __launch_bounds__(256) void k_gemm_bt(
    const u16* __restrict__ A, const u16* __restrict__ Bt,
    const float* __restrict__ bias, void* __restrict__ Cout,
    int M, int N, int K) {
  __shared__ __align__(16) u16 sA[128][40];
  __shared__ __align__(16) u16 sB[128][40];
  int t = threadIdx.x;
  int l = t & 63, w = t >> 6, lo = l & 15, hi = l >> 4;
  int m0 = blockIdx.y * 128, n0 = blockIdx.x * 128;
  int wm = (w >> 1) * 64, wn = (w & 1) * 64;
  int sr = t >> 1, sh = (t & 1) * 16;
  const u16* pa = A + (size_t)(m0 + sr) * K + sh;
  const u16* pb = Bt + (size_t)(n0 + sr) * K + sh;
  f32x4 acc[4][4] = {};
  us8 ra0 = *(const us8*)(pa), ra1 = *(const us8*)(pa + 8);
  us8 rb0 = *(const us8*)(pb), rb1 = *(const us8*)(pb + 8);
  int nk = K >> 5;
  for (int ks = 0; ks < nk; ++ks) {
    __syncthreads();
    *(us8*)&sA[sr][sh] = ra0; *(us8*)&sA[sr][sh + 8] = ra1;
    *(us8*)&sB[sr][sh] = rb0; *(us8*)&sB[sr][sh + 8] = rb1;
    if (ks + 1 < nk) {
      int off = (ks + 1) * 32;
      ra0 = *(const us8*)(pa + off); ra1 = *(const us8*)(pa + off + 8);
      rb0 = *(const us8*)(pb + off); rb1 = *(const us8*)(pb + off + 8);
    }
    __syncthreads();
    f16x8 af[4], bf[4];
#pragma unroll
    for (int mi = 0; mi < 4; ++mi) af[mi] = *(const f16x8*)&sA[wm + mi * 16 + lo][hi * 8];
#pragma unroll
    for (int ni = 0; ni < 4; ++ni) bf[ni] = *(const f16x8*)&sB[wn + ni * 16 + lo][hi * 8];
#pragma unroll
    for (int mi = 0; mi < 4; ++mi)
#pragma unroll
      for (int ni = 0; ni < 4; ++ni)
        acc[mi][ni] = __builtin_amdgcn_mfma_f32_16x16x32_f16(af[mi], bf[ni], acc[mi][ni], 0, 0, 0);
  }
#pragma unroll
  for (int mi = 0; mi < 4; ++mi)
#pragma unroll
    for (int ni = 0; ni < 4; ++ni) {
      int row = m0 + wm + mi * 16 + hi * 4;
      int col = n0 + wn + ni * 16 + lo;
      float bv = bias ? bias[col] : 0.0f;
#pragma unroll
      for (int rr = 0; rr < 4; ++rr) {
        float v = acc[mi][ni][rr] + bv;
        if (OUTF32) ((float*)Cout)[(size_t)(row + rr) * N + col] = v;
        else        ((u16*)Cout)[(size_t)(row + rr) * N + col] = f2h(v);
      }
    }
}

// ---------------- per-token: +bias, per-head RMSNorm, 2D RoPE, scatter to head-major ----------------
__global__ __launch_bounds__(256) void k_norm_rope(
    const u16* __restrict__ qkv,
    const float* __restrict__ q_b, const float* __restrict__ kv_b,
    const float* __restrict__ q_s, const float* __restrict__ k_s,
    u16* __restrict__ qp, u16* __restrict__ kp, u16* __restrict__ vn) {
  __shared__ float s_q[DMODEL], s_k[DMODEL], s_v[DMODEL];
  __shared__ float cs[4][18];
  int t = threadIdx.x;
  int tok = blockIdx.x;
  if (t < 36) {
    int i = t < 18 ? t : t - 18;
    float f = exp2f(-(float)i * (6.6438561897747247f / 9.0f));  // 100^(-i/9)
    float pos = (t < 18) ? (float)(tok >> 6) : (float)(tok & 63);
    float s, c;
    sincosf(pos * f, &s, &c);
    if (t < 18) { cs[0][i] = c; cs[1][i] = s; }
    else        { cs[2][i] = c; cs[3][i] = s; }
  }
  const u16* rowp = qkv + (size_t)tok * NQKV;
  for (int idx = t; idx < DMODEL; idx += 256) {
    s_q[idx] = h2f(rowp[idx]) + q_b[idx];
    s_k[idx] = h2f(rowp[DMODEL + idx]) + kv_b[idx];
    s_v[idx] = h2f(rowp[2 * DMODEL + idx]) + kv_b[DMODEL + idx];
  }
  __syncthreads();
  int h = t >> 4, sub = t & 15;
  int base = h * HD;
  float aq = 0, ak = 0, av = 0;
#pragma unroll
  for (int j = 0; j < 5; ++j) {
    int idx = sub + 16 * j;
    if (idx < HD) {
      float a = s_q[base + idx], b = s_k[base + idx], c = s_v[base + idx];
      aq += a * a; ak += b * b; av += c * c;
    }
  }
#pragma unroll
  for (int m = 1; m <= 8; m <<= 1) {
    aq += __shfl_xor(aq, m, 64);
    ak += __shfl_xor(ak, m, 64);
    av += __shfl_xor(av, m, 64);
  }
  float rq = rsqrtf(aq / 72.f + 1e-6f);
  float rk = rsqrtf(ak / 72.f + 1e-6f);
  float rv = rsqrtf(av / 72.f + 1e-6f);
  size_t ob96 = ((size_t)h * LSEQ + tok) * HP96;
  size_t ob80 = ((size_t)h * LSEQ + tok) * HP80;
#pragma unroll
  for (int j = 0; j < 6; ++j) {
    int idx = sub + 16 * j;
    float oq = 0.f, ok = 0.f;
    if (idx < HD) {
      int sec = idx >= 36;
      int loc = idx - sec * 36;
      int i = loc >= 18 ? loc - 18 : loc;
      float c = cs[sec * 2 + 0][i], s = cs[sec * 2 + 1][i];
      int p1 = sec * 36 + i, p2 = p1 + 18;
      float q1 = s_q[base + p1] * rq * (1.f + q_s[p1]);
      float q2 = s_q[base + p2] * rq * (1.f + q_s[p2]);
      float k1 = s_k[base + p1] * rk * (1.f + k_s[p1]);
      float k2 = s_k[base + p2] * rk * (1.f + k_s[p2]);
      if (loc < 18) { oq = q1 * c - q2 * s; ok = k1 * c - k2 * s; }
      else          { oq = q1 * s + q2 * c; ok = k1 * s + k2 * c; }
    }
    qp[ob96 + idx] = f2h(oq);
    kp[ob96 + idx] = f2h(ok);
  }
#pragma unroll
  for (int j = 0; j < 5; ++j) {
    int idx = sub + 16 * j;
    // h-slot 72 carries 1.0 so PV's MFMA accumulates the softmax denominator for free
    float ov = (idx < HD) ? s_v[base + idx] * rv : (idx == 72 ? 1.0f : 0.f);
    vn[ob80 + idx] = f2h(ov);
  }
}

// ---------------- vt[n][h][key] = vn[n][key][h] ----------------
__global__ __launch_bounds__(256) void k_transp_v(const u16* __restrict__ vn, u16* __restrict__ vt) {
  __shared__ u16 tl[64][81];
  int head = blockIdx.y, k0 = blockIdx.x * 64;
  int t = threadIdx.x;
  for (int p = t; p < 64 * 80; p += 256) {
    int r = p / 80, c = p % 80;
    tl[r][c] = vn[((size_t)head * LSEQ + k0 + r) * HP80 + c];
  }
  __syncthreads();
  for (int p = t; p < 80 * 64; p += 256) {
    int hh = p >> 6, kk = p & 63;
    vt[((size_t)head * HP80 + hh) * LSEQ + k0 + kk] = tl[kk][hh];
  }
}

// ---------------- flash attention: 1 wave per (head, 32 q-rows); no LDS, no barriers ----------------
// Grid = NH*(LSEQ/32) = 2048 blocks of 64 threads -> 8 waves/CU (2/SIMD), ~200 VGPR.
// Decode: c=id&7 (XCD lane), r=id>>3 in [0,256): qb=r&127, head = c + 8*(r>>7)
//   -> heads {c, c+8} pinned to XCD c, K/V L2-resident (2.8 MB / 4 MB L2).
// Q persistent in registers. K,V double-buffered global->register (prefetch next 32-key
// tile during current tile's compute; running pointers + imm offsets, no per-iter muls).
// S = mfma(K,Q): lane-local softmax for q=lo. P packed in-register is directly PV's
// B-operand; V loaded key-permuted to match: register j <-> key 16*(j>>2)+4*hi+(j&3).
// V h-row 72 is all-ones -> oacc row 72 accumulates the softmax denominator;
// defer-max (THR=8) skips most rescales.
__global__ __launch_bounds__(64, 2) void k_flash(
    const u16* __restrict__ qp, const u16* __restrict__ kp,
    const u16* __restrict__ vt, u16* __restrict__ attb) {
  int l = threadIdx.x;
  int lo = l & 15, hi = l >> 4;
  int id = blockIdx.x;
  int r = id >> 3;
  int qb = r & 127, head = ((r >> 7) << 3) + (id & 7);
  const float L2E = 1.4426950408889634f;

  const u16* qbase = qp + ((size_t)head * LSEQ + (size_t)qb * 32) * HP96;
  f16x8 qf[2][3];
#pragma unroll
  for (int g = 0; g < 2; ++g)
#pragma unroll
    for (int c = 0; c < 3; ++c)
      qf[g][c] = *(const f16x8*)&qbase[(g * 16 + lo) * HP96 + c * 32 + hi * 8];

  f32x4 oacc[2][5] = {};
  float mrun[2];
#pragma unroll
  for (int g = 0; g < 2; ++g) mrun[g] = -__builtin_inff();

  // running pointers: K = one base + imm offsets (kg*16*96 + c*32 elems, max 3200B);
  // V = 5 bases (one per ht) + imm 0/32 elems.
  const u16* kptr = kp + (size_t)head * LSEQ * HP96 + lo * HP96 + hi * 8;
  const u16* vptr[5];
#pragma unroll
  for (int ht = 0; ht < 5; ++ht)
    vptr[ht] = vt + ((size_t)head * HP80 + 16 * ht + lo) * LSEQ + hi * 4;

  us8 kcur[2][3], knxt[2][3];
  us4 vcur[5][2], vnxt[5][2];
#pragma unroll
  for (int kg = 0; kg < 2; ++kg)
#pragma unroll
    for (int c = 0; c < 3; ++c)
      kcur[kg][c] = *(const us8*)(kptr + kg * 16 * HP96 + c * 32);
#pragma unroll
  for (int ht = 0; ht < 5; ++ht) {
    vcur[ht][0] = *(const us4*)(vptr[ht]);
    vcur[ht][1] = *(const us4*)(vptr[ht] + 16);
  }
  kptr += 32 * HP96;
#pragma unroll
  for (int ht = 0; ht < 5; ++ht) vptr[ht] += 32;

  for (int kb = 0; kb < LSEQ; kb += 32) {
    // ---- prefetch next tile into regs (consumed next iter) ----
    if (kb + 32 < LSEQ) {
#pragma unroll
      for (int kg = 0; kg < 2; ++kg)
#pragma unroll
        for (int c = 0; c < 3; ++c)
          knxt[kg][c] = *(const us8*)(kptr + kg * 16 * HP96 + c * 32);
#pragma unroll
      for (int ht = 0; ht < 5; ++ht) {
        vnxt[ht][0] = *(const us4*)(vptr[ht]);
        vnxt[ht][1] = *(const us4*)(vptr[ht] + 16);
      }
      kptr += 32 * HP96;
#pragma unroll
      for (int ht = 0; ht < 5; ++ht) vptr[ht] += 32;
    }
    // ---- QK^T: lane holds S[key = kb + 16*kg + hi*4 + rr][q = g*16 + lo] ----
    f32x4 sacc[2][2] = {};
#pragma unroll
    for (int c = 0; c < 3; ++c)
#pragma unroll
      for (int g = 0; g < 2; ++g)
#pragma unroll
        for (int kg = 0; kg < 2; ++kg)
          sacc[g][kg] = __builtin_amdgcn_mfma_f32_16x16x32_f16(
              __builtin_bit_cast(f16x8, kcur[kg][c]), qf[g][c], sacc[g][kg], 0, 0, 0);
    // ---- tile max per q (lane-local + 2 shfl) ----
    float mt[2];
#pragma unroll
    for (int g = 0; g < 2; ++g) {
      float a = fmaxf(fmaxf(fmaxf(sacc[g][0][0], sacc[g][0][1]), sacc[g][0][2]), sacc[g][0][3]);
      float b = fmaxf(fmaxf(fmaxf(sacc[g][1][0], sacc[g][1][1]), sacc[g][1][2]), sacc[g][1][3]);
      float m = fmaxf(a, b);
      m = fmaxf(m, __shfl_xor(m, 16, 64));
      m = fmaxf(m, __shfl_xor(m, 32, 64));
      mt[g] = m;
    }
    // ---- defer-max: rescale only when some row's max grew by > 8 ----
    bool need = (mt[0] > mrun[0] + 8.f) | (mt[1] > mrun[1] + 8.f);
    if (__any(need)) {
#pragma unroll
      for (int g = 0; g < 2; ++g) {
        float mn = fmaxf(mrun[g], mt[g]);
        float al = exp2f((mrun[g] - mn) * L2E);
        mrun[g] = mn;
#pragma unroll
        for (int ht = 0; ht < 5; ++ht)
#pragma unroll
          for (int rr = 0; rr < 4; ++rr) oacc[g][ht][rr] *= al;
      }
    }
    // ---- exp + pack + PV per group (p <= e^8, fits f16) ----
#pragma unroll
    for (int g = 0; g < 2; ++g) {
      float nm = -mrun[g] * L2E;
      float p[2][4];
#pragma unroll
      for (int kg = 0; kg < 2; ++kg)
#pragma unroll
        for (int rr = 0; rr < 4; ++rr)
          p[kg][rr] = exp2f(__builtin_fmaf(sacc[g][kg][rr], L2E, nm));
      u32x4 pw = {__builtin_bit_cast(u32, __builtin_amdgcn_cvt_pkrtz(p[0][0], p[0][1])),
                  __builtin_bit_cast(u32, __builtin_amdgcn_cvt_pkrtz(p[0][2], p[0][3])),
                  __builtin_bit_cast(u32, __builtin_amdgcn_cvt_pkrtz(p[1][0], p[1][1])),
                  __builtin_bit_cast(u32, __builtin_amdgcn_cvt_pkrtz(p[1][2], p[1][3]))};
      f16x8 pb = __builtin_bit_cast(f16x8, pw);
#pragma unroll
      for (int ht = 0; ht < 5; ++ht) {
        f16x8 av = __builtin_bit_cast(f16x8,
            __builtin_shufflevector(vcur[ht][0], vcur[ht][1], 0, 1, 2, 3, 4, 5, 6, 7));
        oacc[g][ht] = __builtin_amdgcn_mfma_f32_16x16x32_f16(av, pb, oacc[g][ht], 0, 0, 0);
      }
    }
    // ---- rotate buffers (static copies; compiler renames) ----
#pragma unroll
    for (int kg = 0; kg < 2; ++kg)
#pragma unroll
      for (int c = 0; c < 3; ++c) kcur[kg][c] = knxt[kg][c];
#pragma unroll
    for (int ht = 0; ht < 5; ++ht) {
      vcur[ht][0] = vnxt[ht][0];
      vcur[ht][1] = vnxt[ht][1];
    }
  }
  // ---- epilogue: denominator lives at h=72 (ht=4, hi=2, rr=0) of each q-column ----
#pragma unroll
  for (int g = 0; g < 2; ++g) {
    float den = __shfl(oacc[g][4][0], lo + 32, 64);
    float inv = 1.f / den;
    int row = qb * 32 + g * 16 + lo;
    u16* orow = attb + (size_t)row * DMODEL + head * HD;
#pragma unroll
    for (int ht = 0; ht < 5; ++ht)
#pragma unroll
      for (int rr = 0; rr < 4; ++rr) {
        int h = 16 * ht + 4 * hi + rr;
        if (h < HD) orow[h] = f2h(oacc[g][ht][rr] * inv);
      }
  }
}

extern "C" void kernel_launch(void* const* d_in, const int* in_sizes, int n_in,
                              void* d_out, int out_size, void* d_ws, size_t ws_size,
                              hipStream_t stream) {
  const float* x    = (const float*)d_in[0];
  const float* q_w  = (const float*)d_in[1];
  const float* q_b  = (const float*)d_in[2];
  const float* kv_w = (const float*)d_in[3];
  const float* kv_b = (const float*)d_in[4];
  const float* o_w  = (const float*)d_in[5];
  const float* o_b  = (const float*)d_in[6];
  const float* q_s  = (const float*)d_in[7];
  const float* k_s  = (const float*)d_in[8];
  char* ws = (char*)d_ws;
  u16* xb   = (u16*)(ws + 0);          // 9,437,184   x in f16
  u16* wT   = (u16*)(ws + 9437184);    // 7,962,624   [q_w^T ; kv_w^T] f16 [3456][1152]
  u16* oT   = (u16*)(ws + 17399808);   // 2,654,208   o_w^T f16
  u16* qkvb = (u16*)(ws + 20054016);   // 28,311,552  qkv pre-norm f16 [4096][3456]
  u16* qp   = (u16*)(ws + 48365568);   // 12,582,912  q head-major [16][4096][96]
  u16* kp   = (u16*)(ws + 60948480);   // 12,582,912  k head-major
  u16* vn   = (u16*)(ws + 73531392);   // 10,485,760  v head-major [16][4096][80]
  u16* vt   = (u16*)(ws + 0);          // reuse xb+wT after QKV GEMM: [16][80][4096]
  u16* attb = (u16*)(ws + 20054016);   // reuse qkvb after norm: attn out f16 [4096][1152]

  k_cvt_f16<<<2048, 256, 0, stream>>>(x, xb, LSEQ * DMODEL / 4);
  k_transp_w<<<dim3(36, 36), 256, 0, stream>>>(q_w, wT, DMODEL, DMODEL);
  k_transp_w<<<dim3(72, 36), 256, 0, stream>>>(kv_w, wT + (size_t)DMODEL * DMODEL, DMODEL, 2 * DMODEL);
  k_transp_w<<<dim3(36, 36), 256, 0, stream>>>(o_w, oT, DMODEL, DMODEL);
  k_gemm_bt<false><<<dim3(27, 32), 256, 0, stream>>>(xb, wT, nullptr, qkvb, LSEQ, NQKV, DMODEL);
  k_norm_rope<<<LSEQ, 256, 0, stream>>>(qkvb, q_b, kv_b, q_s, k_s, qp, kp, vn);
  k_transp_v<<<dim3(64, 16), 256, 0, stream>>>(vn, vt);
  k_flash<<<2048, 64, 0, stream>>>(qp, kp, vt, attb);
  k_gemm_bt<true><<<dim3(9, 32), 256, 0, stream>>>(attb, oT, o_b, (float*)d_out, LSEQ, DMODEL, DMODEL);
}

// Round 6
// 280.292 us; speedup vs baseline: 1.8015x; 1.8015x over previous
//
#include <hip/hip_runtime.h>
#include <cstdint>
#include <cstddef>

#define LSEQ 4096
#define DMODEL 1152
#define NH 16
#define HD 72
#define HP96 96
#define HP80 80
#define NQKV 3456

typedef unsigned short u16;
typedef unsigned int u32;
typedef __attribute__((ext_vector_type(4))) float f32x4;
typedef __attribute__((ext_vector_type(4))) u32 u32x4;
typedef _Float16 f16x8 __attribute__((ext_vector_type(8), may_alias));
typedef unsigned short us8 __attribute__((ext_vector_type(8), may_alias));
typedef unsigned short us4 __attribute__((ext_vector_type(4), may_alias));

static __device__ __forceinline__ u16 f2h(float f) {
  _Float16 h = (_Float16)f;
  return __builtin_bit_cast(u16, h);
}
static __device__ __forceinline__ float h2f(u16 b) {
  return (float)__builtin_bit_cast(_Float16, b);
}

// ---------------- f32 -> f16 elementwise ----------------
__global__ void k_cvt_f16(const float* __restrict__ src, u16* __restrict__ dst, int n4) {
  int i = blockIdx.x * blockDim.x + threadIdx.x;
  int stride = gridDim.x * blockDim.x;
  for (; i < n4; i += stride) {
    float4 v = ((const float4*)src)[i];
    us4 o; o[0] = f2h(v.x); o[1] = f2h(v.y); o[2] = f2h(v.z); o[3] = f2h(v.w);
    ((us4*)dst)[i] = o;
  }
}

// ---------------- dst[n][k] = (f16) src[k][n]  (weight transpose) ----------------
__global__ void k_transp_w(const float* __restrict__ src, u16* __restrict__ dst, int K, int N) {
  __shared__ float tile[32][33];
  int tx = threadIdx.x & 31, ty = threadIdx.x >> 5;
  int n0 = blockIdx.x * 32, k0 = blockIdx.y * 32;
#pragma unroll
  for (int j = 0; j < 4; ++j)
    tile[ty + j * 8][tx] = src[(size_t)(k0 + ty + j * 8) * N + n0 + tx];
  __syncthreads();
#pragma unroll
  for (int j = 0; j < 4; ++j)
    dst[(size_t)(n0 + ty + j * 8) * K + k0 + tx] = f2h(tile[tx][ty + j * 8]);
}

// ---------------- C[M][N] = A[M][K] @ Bt[N][K]^T (+bias), f16 in, f16/f32 out ----------------
template <bool OUTF32>
__global__ __launch_bounds__(256) void k_gemm_bt(
    const u16* __restrict__ A, const u16* __restrict__ Bt,
    const float* __restrict__ bias, void* __restrict__ Cout,
    int M, int N, int K) {
  __shared__ __align__(16) u16 sA[128][40];
  __shared__ __align__(16) u16 sB[128][40];
  int t = threadIdx.x;
  int l = t & 63, w = t >> 6, lo = l & 15, hi = l >> 4;
  int m0 = blockIdx.y * 128, n0 = blockIdx.x * 128;
  int wm = (w >> 1) * 64, wn = (w & 1) * 64;
  int sr = t >> 1, sh = (t & 1) * 16;
  const u16* pa = A + (size_t)(m0 + sr) * K + sh;
  const u16* pb = Bt + (size_t)(n0 + sr) * K + sh;
  f32x4 acc[4][4] = {};
  us8 ra0 = *(const us8*)(pa), ra1 = *(const us8*)(pa + 8);
  us8 rb0 = *(const us8*)(pb), rb1 = *(const us8*)(pb + 8);
  int nk = K >> 5;
  for (int ks = 0; ks < nk; ++ks) {
    __syncthreads();
    *(us8*)&sA[sr][sh] = ra0; *(us8*)&sA[sr][sh + 8] = ra1;
    *(us8*)&sB[sr][sh] = rb0; *(us8*)&sB[sr][sh + 8] = rb1;
    if (ks + 1 < nk) {
      int off = (ks + 1) * 32;
      ra0 = *(const us8*)(pa + off); ra1 = *(const us8*)(pa + off + 8);
      rb0 = *(const us8*)(pb + off); rb1 = *(const us8*)(pb + off + 8);
    }
    __syncthreads();
    f16x8 af[4], bf[4];
#pragma unroll
    for (int mi = 0; mi < 4; ++mi) af[mi] = *(const f16x8*)&sA[wm + mi * 16 + lo][hi * 8];
#pragma unroll
    for (int ni = 0; ni < 4; ++ni) bf[ni] = *(const f16x8*)&sB[wn + ni * 16 + lo][hi * 8];
#pragma unroll
    for (int mi = 0; mi < 4; ++mi)
#pragma unroll
      for (int ni = 0; ni < 4; ++ni)
        acc[mi][ni] = __builtin_amdgcn_mfma_f32_16x16x32_f16(af[mi], bf[ni], acc[mi][ni], 0, 0, 0);
  }
#pragma unroll
  for (int mi = 0; mi < 4; ++mi)
#pragma unroll
    for (int ni = 0; ni < 4; ++ni) {
      int row = m0 + wm + mi * 16 + hi * 4;
      int col = n0 + wn + ni * 16 + lo;
      float bv = bias ? bias[col] : 0.0f;
#pragma unroll
      for (int rr = 0; rr < 4; ++rr) {
        float v = acc[mi][ni][rr] + bv;
        if (OUTF32) ((float*)Cout)[(size_t)(row + rr) * N + col] = v;
        else        ((u16*)Cout)[(size_t)(row + rr) * N + col] = f2h(v);
      }
    }
}

// ---------------- per-token: +bias, per-head RMSNorm, 2D RoPE, scatter to head-major ----------------
__global__ __launch_bounds__(256) void k_norm_rope(
    const u16* __restrict__ qkv,
    const float* __restrict__ q_b, const float* __restrict__ kv_b,
    const float* __restrict__ q_s, const float* __restrict__ k_s,
    u16* __restrict__ qp, u16* __restrict__ kp, u16* __restrict__ vn) {
  __shared__ float s_q[DMODEL], s_k[DMODEL], s_v[DMODEL];
  __shared__ float cs[4][18];
  int t = threadIdx.x;
  int tok = blockIdx.x;
  if (t < 36) {
    int i = t < 18 ? t : t - 18;
    float f = exp2f(-(float)i * (6.6438561897747247f / 9.0f));  // 100^(-i/9)
    float pos = (t < 18) ? (float)(tok >> 6) : (float)(tok & 63);
    float s, c;
    sincosf(pos * f, &s, &c);
    if (t < 18) { cs[0][i] = c; cs[1][i] = s; }
    else        { cs[2][i] = c; cs[3][i] = s; }
  }
  const u16* rowp = qkv + (size_t)tok * NQKV;
  for (int idx = t; idx < DMODEL; idx += 256) {
    s_q[idx] = h2f(rowp[idx]) + q_b[idx];
    s_k[idx] = h2f(rowp[DMODEL + idx]) + kv_b[idx];
    s_v[idx] = h2f(rowp[2 * DMODEL + idx]) + kv_b[DMODEL + idx];
  }
  __syncthreads();
  int h = t >> 4, sub = t & 15;
  int base = h * HD;
  float aq = 0, ak = 0, av = 0;
#pragma unroll
  for (int j = 0; j < 5; ++j) {
    int idx = sub + 16 * j;
    if (idx < HD) {
      float a = s_q[base + idx], b = s_k[base + idx], c = s_v[base + idx];
      aq += a * a; ak += b * b; av += c * c;
    }
  }
#pragma unroll
  for (int m = 1; m <= 8; m <<= 1) {
    aq += __shfl_xor(aq, m, 64);
    ak += __shfl_xor(ak, m, 64);
    av += __shfl_xor(av, m, 64);
  }
  float rq = rsqrtf(aq / 72.f + 1e-6f);
  float rk = rsqrtf(ak / 72.f + 1e-6f);
  float rv = rsqrtf(av / 72.f + 1e-6f);
  size_t ob96 = ((size_t)h * LSEQ + tok) * HP96;
  size_t ob80 = ((size_t)h * LSEQ + tok) * HP80;
#pragma unroll
  for (int j = 0; j < 6; ++j) {
    int idx = sub + 16 * j;
    float oq = 0.f, ok = 0.f;
    if (idx < HD) {
      int sec = idx >= 36;
      int loc = idx - sec * 36;
      int i = loc >= 18 ? loc - 18 : loc;
      float c = cs[sec * 2 + 0][i], s = cs[sec * 2 + 1][i];
      int p1 = sec * 36 + i, p2 = p1 + 18;
      float q1 = s_q[base + p1] * rq * (1.f + q_s[p1]);
      float q2 = s_q[base + p2] * rq * (1.f + q_s[p2]);
      float k1 = s_k[base + p1] * rk * (1.f + k_s[p1]);
      float k2 = s_k[base + p2] * rk * (1.f + k_s[p2]);
      if (loc < 18) { oq = q1 * c - q2 * s; ok = k1 * c - k2 * s; }
      else          { oq = q1 * s + q2 * c; ok = k1 * s + k2 * c; }
    }
    qp[ob96 + idx] = f2h(oq);
    kp[ob96 + idx] = f2h(ok);
  }
#pragma unroll
  for (int j = 0; j < 5; ++j) {
    int idx = sub + 16 * j;
    // h-slot 72 carries 1.0 so PV's MFMA accumulates the softmax denominator for free
    float ov = (idx < HD) ? s_v[base + idx] * rv : (idx == 72 ? 1.0f : 0.f);
    vn[ob80 + idx] = f2h(ov);
  }
}

// ---------------- V -> fragment-major global layout ----------------
// vf[head][kb32][ht][lane][8]: lane (lo=l&15, hi=l>>4), elem j holds
// V[h = 16*ht + lo][key = kb*32 + (j>>2)*16 + hi*4 + (j&3)].
// A wave's PV A-fragment load is then 5 fully-contiguous 1KB lines per 32-key half.
__global__ __launch_bounds__(256) void k_vfrag(const u16* __restrict__ vn, u16* __restrict__ vf) {
  __shared__ u16 tl[32][84];  // [key_local][h] pad 80->84
  int head = blockIdx.y, kb = blockIdx.x;
  int t = threadIdx.x;
  const u16* src = vn + ((size_t)head * LSEQ + kb * 32) * HP80;
  for (int p = t; p < 32 * 20; p += 256) {
    int rr = p / 20, c4 = p % 20;
    *(us4*)&tl[rr][c4 * 4] = *(const us4*)(src + rr * HP80 + c4 * 4);
  }
  __syncthreads();
  u16* dst = vf + ((size_t)head * 128 + kb) * 2560;
  for (int u = t; u < 320; u += 256) {
    int ht = u >> 6, ll = u & 63, lo2 = ll & 15, hi2 = ll >> 4;
    us8 o;
#pragma unroll
    for (int j = 0; j < 8; ++j)
      o[j] = tl[(j >> 2) * 16 + hi2 * 4 + (j & 3)][ht * 16 + lo2];
    *(us8*)&dst[(size_t)u * 8] = o;
  }
}

// ---------------- flash attention: 4 waves x 32 q-rows; K via LDS, V direct from vf ----------------
// Grid = 512 blocks of 256. Decode: c=id&7 (XCD lane), r=id>>3 in [0,64):
//   qb=r&31, head = (r>>5)*8 + c -> heads {c, c+8} pinned to XCD c (K/V L2-resident).
// K staged to LDS per 64-key tile (shared by 4 waves; reg-prefetch next tile across the
// barrier — R2-validated pattern). V read directly global->reg from fragment-major vf
// (coalesced 1KB lines), double-buffered per 32-key half. S = mfma(K,Q): lane-local
// softmax for q=lo (2 shfl). P packed via cvt_pkrtz is directly PV's B-operand (vf bakes
// the key permutation). V h-row 72 is all-ones -> oacc accumulates the denominator.
// defer-max (THR=8) skips most rescales.
__global__ __launch_bounds__(256, 2) void k_flash(
    const u16* __restrict__ qp, const u16* __restrict__ kp,
    const u16* __restrict__ vf, u16* __restrict__ attb) {
  __shared__ __align__(16) u16 sK[64][104];  // [key][hdim] pad 96->104
  int t = threadIdx.x;
  int l = t & 63, w = t >> 6, lo = l & 15, hi = l >> 4;
  int id = blockIdx.x, r = id >> 3;
  int qb = r & 31, head = ((r >> 5) << 3) + (id & 7);
  const float L2E = 1.4426950408889634f;

  // Q persistent: rows qb*128 + w*32 + g*16 + lo
  const u16* qbase = qp + ((size_t)head * LSEQ + qb * 128 + w * 32 + lo) * HP96 + hi * 8;
  f16x8 qf[2][3];
#pragma unroll
  for (int g = 0; g < 2; ++g)
#pragma unroll
    for (int c = 0; c < 3; ++c)
      qf[g][c] = *(const f16x8*)(qbase + g * 16 * HP96 + c * 32);

  f32x4 oacc[2][5] = {};
  float mrun[2];
#pragma unroll
  for (int g = 0; g < 2; ++g) mrun[g] = -__builtin_inff();

  // K staging: 4 threads/row, 24 u16 each
  int sr_ = t >> 2, sq4 = (t & 3) * 24;
  const u16* kptr = kp + ((size_t)head * LSEQ + sr_) * HP96 + sq4;
  us8 kx0 = *(const us8*)(kptr), kx1 = *(const us8*)(kptr + 8), kx2 = *(const us8*)(kptr + 16);

  // V fragment stream: one 5120B frame per 32-key half
  const u16* vptr = vf + (size_t)head * 128 * 2560 + (size_t)l * 8;
  us8 vA[5], vB[5];
#pragma unroll
  for (int ht = 0; ht < 5; ++ht) vA[ht] = *(const us8*)(vptr + ht * 512);
  vptr += 2560;

  for (int kt = 0; kt < 64; ++kt) {
    __syncthreads();
    *(us8*)&sK[sr_][sq4] = kx0; *(us8*)&sK[sr_][sq4 + 8] = kx1; *(us8*)&sK[sr_][sq4 + 16] = kx2;
    if (kt < 63) {  // reg-prefetch next K tile; stays in flight across the barrier
      kx0 = *(const us8*)(kptr + 6144);
      kx1 = *(const us8*)(kptr + 6144 + 8);
      kx2 = *(const us8*)(kptr + 6144 + 16);
      kptr += 6144;
    }
    __syncthreads();
    // ---- QK^T: lane holds S[key = 16*nt + 4*hi + rr][q = g*16 + lo] ----
    f32x4 sacc[2][4] = {};
#pragma unroll
    for (int c = 0; c < 3; ++c)
#pragma unroll
      for (int nt = 0; nt < 4; ++nt) {
        f16x8 bk = *(const f16x8*)&sK[lo + 16 * nt][c * 32 + hi * 8];
#pragma unroll
        for (int g = 0; g < 2; ++g)
          sacc[g][nt] = __builtin_amdgcn_mfma_f32_16x16x32_f16(bk, qf[g][c], sacc[g][nt], 0, 0, 0);
      }
    // ---- tile max per q (lane-local + 2 shfl) ----
    float mt[2];
#pragma unroll
    for (int g = 0; g < 2; ++g) {
      float m = fmaxf(fmaxf(fmaxf(sacc[g][0][0], sacc[g][0][1]), sacc[g][0][2]), sacc[g][0][3]);
#pragma unroll
      for (int nt = 1; nt < 4; ++nt)
        m = fmaxf(m, fmaxf(fmaxf(fmaxf(sacc[g][nt][0], sacc[g][nt][1]), sacc[g][nt][2]), sacc[g][nt][3]));
      m = fmaxf(m, __shfl_xor(m, 16, 64));
      m = fmaxf(m, __shfl_xor(m, 32, 64));
      mt[g] = m;
    }
    // ---- defer-max: rescale only when some row's max grew by > 8 ----
    bool need = (mt[0] > mrun[0] + 8.f) | (mt[1] > mrun[1] + 8.f);
    if (__any(need)) {
#pragma unroll
      for (int g = 0; g < 2; ++g) {
        float mn = fmaxf(mrun[g], mt[g]);
        float al = exp2f((mrun[g] - mn) * L2E);
        mrun[g] = mn;
#pragma unroll
        for (int ht = 0; ht < 5; ++ht)
#pragma unroll
          for (int rr = 0; rr < 4; ++rr) oacc[g][ht][rr] *= al;
      }
    }
    // ---- per 32-key half: prefetch next V frame, exp+pack P, PV ----
#pragma unroll
    for (int kc = 0; kc < 2; ++kc) {
#pragma unroll
      for (int ht = 0; ht < 5; ++ht) vB[ht] = *(const us8*)(vptr + ht * 512);
      vptr += 2560;  // last half prefetches one dead frame (lands in dead ws region)
#pragma unroll
      for (int g = 0; g < 2; ++g) {
        float nm = -mrun[g] * L2E;
        float p0[4], p1[4];
#pragma unroll
        for (int rr = 0; rr < 4; ++rr) {
          p0[rr] = exp2f(__builtin_fmaf(sacc[g][2 * kc][rr], L2E, nm));
          p1[rr] = exp2f(__builtin_fmaf(sacc[g][2 * kc + 1][rr], L2E, nm));
        }
        u32x4 pw = {__builtin_bit_cast(u32, __builtin_amdgcn_cvt_pkrtz(p0[0], p0[1])),
                    __builtin_bit_cast(u32, __builtin_amdgcn_cvt_pkrtz(p0[2], p0[3])),
                    __builtin_bit_cast(u32, __builtin_amdgcn_cvt_pkrtz(p1[0], p1[1])),
                    __builtin_bit_cast(u32, __builtin_amdgcn_cvt_pkrtz(p1[2], p1[3]))};
        f16x8 pb = __builtin_bit_cast(f16x8, pw);
#pragma unroll
        for (int ht = 0; ht < 5; ++ht)
          oacc[g][ht] = __builtin_amdgcn_mfma_f32_16x16x32_f16(
              __builtin_bit_cast(f16x8, vA[ht]), pb, oacc[g][ht], 0, 0, 0);
      }
#pragma unroll
      for (int ht = 0; ht < 5; ++ht) vA[ht] = vB[ht];
    }
  }
  // ---- epilogue: denominator lives at h=72 (ht=4, hi=2, rr=0) of each q-column ----
#pragma unroll
  for (int g = 0; g < 2; ++g) {
    float den = __shfl(oacc[g][4][0], lo + 32, 64);
    float inv = 1.f / den;
    int row = qb * 128 + w * 32 + g * 16 + lo;
    u16* orow = attb + (size_t)row * DMODEL + head * HD;
#pragma unroll
    for (int ht = 0; ht < 5; ++ht)
#pragma unroll
      for (int rr = 0; rr < 4; ++rr) {
        int h = 16 * ht + 4 * hi + rr;
        if (h < HD) orow[h] = f2h(oacc[g][ht][rr] * inv);
      }
  }
}

extern "C" void kernel_launch(void* const* d_in, const int* in_sizes, int n_in,
                              void* d_out, int out_size, void* d_ws, size_t ws_size,
                              hipStream_t stream) {
  const float* x    = (const float*)d_in[0];
  const float* q_w  = (const float*)d_in[1];
  const float* q_b  = (const float*)d_in[2];
  const float* kv_w = (const float*)d_in[3];
  const float* kv_b = (const float*)d_in[4];
  const float* o_w  = (const float*)d_in[5];
  const float* o_b  = (const float*)d_in[6];
  const float* q_s  = (const float*)d_in[7];
  const float* k_s  = (const float*)d_in[8];
  char* ws = (char*)d_ws;
  u16* xb   = (u16*)(ws + 0);          // 9,437,184   x in f16 (dead after GEMM1)
  u16* wT   = (u16*)(ws + 9437184);    // 7,962,624   [q_w^T ; kv_w^T] f16 (dead after GEMM1)
  u16* oT   = (u16*)(ws + 17399808);   // 2,654,208   o_w^T f16 (live until GEMM2)
  u16* qkvb = (u16*)(ws + 20054016);   // 28,311,552  qkv pre-norm f16 [4096][3456]
  u16* qp   = (u16*)(ws + 48365568);   // 12,582,912  q head-major [16][4096][96]
  u16* kp   = (u16*)(ws + 60948480);   // 12,582,912  k head-major
  u16* vn   = (u16*)(ws + 73531392);   // 10,485,760  v head-major [16][4096][80]
  u16* vfb  = (u16*)(ws + 0);          // 10,485,760  V fragment-major (reuses xb+wT head)
  u16* attb = (u16*)(ws + 20054016);   // reuse qkvb after norm: attn out f16 [4096][1152]

  k_cvt_f16<<<2048, 256, 0, stream>>>(x, xb, LSEQ * DMODEL / 4);
  k_transp_w<<<dim3(36, 36), 256, 0, stream>>>(q_w, wT, DMODEL, DMODEL);
  k_transp_w<<<dim3(72, 36), 256, 0, stream>>>(kv_w, wT + (size_t)DMODEL * DMODEL, DMODEL, 2 * DMODEL);
  k_transp_w<<<dim3(36, 36), 256, 0, stream>>>(o_w, oT, DMODEL, DMODEL);
  k_gemm_bt<false><<<dim3(27, 32), 256, 0, stream>>>(xb, wT, nullptr, qkvb, LSEQ, NQKV, DMODEL);
  k_norm_rope<<<LSEQ, 256, 0, stream>>>(qkvb, q_b, kv_b, q_s, k_s, qp, kp, vn);
  k_vfrag<<<dim3(128, 16), 256, 0, stream>>>(vn, vfb);
  k_flash<<<512, 256, 0, stream>>>(qp, kp, vfb, attb);
  k_gemm_bt<true><<<dim3(9, 32), 256, 0, stream>>>(attb, oT, o_b, (float*)d_out, LSEQ, DMODEL, DMODEL);
}